// Round 14
// baseline (502.062 us; speedup 1.0000x reference)
//
#include <hip/hip_runtime.h>
#include <hip/hip_bf16.h>

typedef __attribute__((ext_vector_type(8))) short short8;
typedef __attribute__((ext_vector_type(4))) float floatx4;
typedef __attribute__((ext_vector_type(16))) float f32x16;
typedef __attribute__((ext_vector_type(2))) unsigned uint2v;

#define B_C 4
#define NEW_C 512
#define CACHE_C 4096
#define TOTAL_C 4608
#define H_C 32
#define HKV_C 8
#define D_C 128
#define HID_C 4096
#define QKV_N 6144

__device__ __forceinline__ unsigned short f2bf(float f) {
  union { float f; unsigned u; } v; v.f = f;
  unsigned r = v.u + 0x7FFFu + ((v.u >> 16) & 1u);
  return (unsigned short)(r >> 16);
}
__device__ __forceinline__ float bf2f(unsigned short h) {
  union { unsigned u; float f; } v; v.u = ((unsigned)h) << 16; return v.f;
}
__device__ __forceinline__ unsigned pack_bf16(float lo, float hi) {
  return ((unsigned)f2bf(hi) << 16) | (unsigned)f2bf(lo);
}
// single v_perm_b32: bf16 pair via truncation (RTZ).
__device__ __forceinline__ unsigned pack_trunc(float lo, float hi) {
  union { float f; unsigned u; } a, b;
  a.f = lo; b.f = hi;
  return __builtin_amdgcn_perm(b.u, a.u, 0x07060302u);
}
__device__ __forceinline__ void gload_lds16(const unsigned short* g, unsigned short* lds) {
  __builtin_amdgcn_global_load_lds(
      (const __attribute__((address_space(1))) unsigned int*)g,
      (__attribute__((address_space(3))) unsigned int*)lds, 16, 0, 0);
}

// ---------------- RMSNorm: x f32 (2048x4096) -> hn bf16 ----------------
__global__ __launch_bounds__(256) void rmsnorm_k(const float* __restrict__ x,
                                                 const float* __restrict__ g,
                                                 unsigned short* __restrict__ hn) {
  const int row = blockIdx.x;
  const int t = threadIdx.x;
  const float4* xr = (const float4*)(x + (size_t)row * 4096);
  float4 v[4];
  float ss = 0.f;
#pragma unroll
  for (int i = 0; i < 4; ++i) {
    v[i] = xr[t + i * 256];
    ss += v[i].x * v[i].x + v[i].y * v[i].y + v[i].z * v[i].z + v[i].w * v[i].w;
  }
#pragma unroll
  for (int m = 1; m < 64; m <<= 1) ss += __shfl_xor(ss, m);
  __shared__ float red[4];
  if ((t & 63) == 0) red[t >> 6] = ss;
  __syncthreads();
  ss = red[0] + red[1] + red[2] + red[3];
  const float inv = rsqrtf(ss * (1.f / 4096.f) + 1e-6f);
  const float4* gw = (const float4*)g;
#pragma unroll
  for (int i = 0; i < 4; ++i) {
    float4 w4 = gw[t + i * 256];
    ushort4 o;
    o.x = f2bf(v[i].x * inv * w4.x);
    o.y = f2bf(v[i].y * inv * w4.y);
    o.z = f2bf(v[i].z * inv * w4.z);
    o.w = f2bf(v[i].w * inv * w4.w);
    *(ushort4*)&hn[(size_t)row * 4096 + (t + i * 256) * 4] = o;
  }
}

// ---- build wqkvT bf16 (6144 x 4096): wqkvT[n][k] = {wq|wk|wv}[k][n] ----
__global__ __launch_bounds__(256) void build_wqkvT_k(const float* __restrict__ wq,
                                                     const float* __restrict__ wk,
                                                     const float* __restrict__ wv,
                                                     unsigned short* __restrict__ out) {
  __shared__ float tile[32][33];
  const int n0 = blockIdx.x * 32, k0 = blockIdx.y * 32;
  const float* src; int ld, nc;
  if (n0 < 4096)      { src = wq; ld = 4096; nc = n0; }
  else if (n0 < 5120) { src = wk; ld = 1024; nc = n0 - 4096; }
  else                { src = wv; ld = 1024; nc = n0 - 5120; }
  const int t = threadIdx.x, r = t >> 3, cv = (t & 7) * 4;
  const float4 v = *(const float4*)&src[(size_t)(k0 + r) * ld + nc + cv];
  tile[r][cv + 0] = v.x; tile[r][cv + 1] = v.y; tile[r][cv + 2] = v.z; tile[r][cv + 3] = v.w;
  __syncthreads();
  ushort4 o;
  o.x = f2bf(tile[cv + 0][r]); o.y = f2bf(tile[cv + 1][r]);
  o.z = f2bf(tile[cv + 2][r]); o.w = f2bf(tile[cv + 3][r]);
  *(ushort4*)&out[(size_t)(n0 + r) * 4096 + k0 + cv] = o;
}

// ---- generic f32->bf16 32x32 transpose: dst[c][r] = src[r][c] ----
__global__ __launch_bounds__(256) void transpose_cvt_k(const float* __restrict__ src,
                                                       long sbs_hi, long sbs_lo, int sld,
                                                       unsigned short* __restrict__ dst,
                                                       long dbs, int dld) {
  __shared__ float tile[32][33];
  const int z = blockIdx.z;
  const long sb = (long)(z >> 3) * sbs_hi + (long)(z & 7) * sbs_lo;
  const long db = (long)z * dbs;
  const int r0 = blockIdx.y * 32, c0 = blockIdx.x * 32;
  const int t = threadIdx.x, r = t >> 3, cv = (t & 7) * 4;
  const float4 v = *(const float4*)&src[sb + (long)(r0 + r) * sld + c0 + cv];
  tile[r][cv + 0] = v.x; tile[r][cv + 1] = v.y; tile[r][cv + 2] = v.z; tile[r][cv + 3] = v.w;
  __syncthreads();
  ushort4 o;
  o.x = f2bf(tile[cv + 0][r]); o.y = f2bf(tile[cv + 1][r]);
  o.z = f2bf(tile[cv + 2][r]); o.w = f2bf(tile[cv + 3][r]);
  *(ushort4*)&dst[db + (long)(c0 + r) * dld + r0 + cv] = o;
}

// ---- u16 32x32 transpose (no convert): dst[c][r] = src[r][c] ----
__global__ __launch_bounds__(256) void transpose_u16_k(const unsigned short* __restrict__ src,
                                                       long sbs, int sld,
                                                       unsigned short* __restrict__ dst,
                                                       long dbs, int dld) {
  __shared__ unsigned short tile[32][36];
  const int z = blockIdx.z;
  const long sb = (long)z * sbs;
  const long db = (long)z * dbs;
  const int r0 = blockIdx.y * 32, c0 = blockIdx.x * 32;
  const int t = threadIdx.x, r = t >> 3, cv = (t & 7) * 4;
  const ushort4 v = *(const ushort4*)&src[sb + (long)(r0 + r) * sld + c0 + cv];
  tile[r][cv + 0] = v.x; tile[r][cv + 1] = v.y; tile[r][cv + 2] = v.z; tile[r][cv + 3] = v.w;
  __syncthreads();
  ushort4 o;
  o.x = tile[cv + 0][r]; o.y = tile[cv + 1][r]; o.z = tile[cv + 2][r]; o.w = tile[cv + 3][r];
  *(ushort4*)&dst[db + (long)(c0 + r) * dld + r0 + cv] = o;
}

// ---- k_cache f32 (B,TOTAL,HKV,D) s<CACHE -> K_all bf16 (B,HKV,TOTAL,D) ----
__global__ __launch_bounds__(256) void cvt_kcache_k(const float* __restrict__ kc,
                                                    unsigned short* __restrict__ Kall) {
  const long i = (long)blockIdx.x * 256 + threadIdx.x;  // over 4*8*4096*32 float4
  const long c = i & 31, s = (i >> 5) & 4095, h = (i >> 17) & 7, b = i >> 20;
  const float4 v = *(const float4*)&kc[((b * 4608 + s) * 8 + h) * 128 + c * 4];
  ushort4 o;
  o.x = f2bf(v.x); o.y = f2bf(v.y); o.z = f2bf(v.z); o.w = f2bf(v.w);
  *(ushort4*)&Kall[((b * 8 + h) * 4608L + s) * 128 + c * 4] = o;
}

// ---- RoPE: qkv bf16 row -> q_rope bf16 (PRE-SCALED by 1/sqrt(D)*log2e), K_all bf16 ----
__global__ __launch_bounds__(256) void rope_k(const unsigned short* __restrict__ qkv,
                                              const float* __restrict__ cosb,
                                              const float* __restrict__ sinb,
                                              unsigned short* __restrict__ qr,
                                              unsigned short* __restrict__ Kall) {
  const float SCL = 0.08838834764831845f * 1.4426950408889634f;  // 1/sqrt(128) * log2(e)
  const int row = blockIdx.x;
  const int b = row >> 9, n = row & 511;
  const unsigned short* src = qkv + (size_t)row * QKV_N;
  const float* cr = cosb + (size_t)row * 128;
  const float* sr = sinb + (size_t)row * 128;
  const int t = threadIdx.x;
#pragma unroll
  for (int i = 0; i < 8; ++i) {  // Q: 32 heads * 64 pairs
    int pid = t + i * 256;
    int hd = pid >> 6, d = pid & 63;
    int idx = hd * 128 + d;
    float a = bf2f(src[idx]), bb = bf2f(src[idx + 64]);
    float c0 = cr[d], s0 = sr[d], c1 = cr[d + 64], s1 = sr[d + 64];
    qr[(size_t)row * 4096 + idx] = f2bf((a * c0 - bb * s0) * SCL);
    qr[(size_t)row * 4096 + idx + 64] = f2bf((bb * c1 + a * s1) * SCL);
  }
#pragma unroll
  for (int i = 0; i < 2; ++i) {  // K: 8 heads * 64 pairs
    int pid = t + i * 256;
    int hd = pid >> 6, d = pid & 63;
    float a = bf2f(src[4096 + hd * 128 + d]), bb = bf2f(src[4096 + hd * 128 + d + 64]);
    float c0 = cr[d], s0 = sr[d], c1 = cr[d + 64], s1 = sr[d + 64];
    long kb = ((long)(b * 8 + hd) * TOTAL_C + CACHE_C + n) * 128 + d;
    Kall[kb] = f2bf(a * c0 - bb * s0);
    Kall[kb + 64] = f2bf(bb * c1 + a * s1);
  }
}

// ====== GEMM 2-phase: C(MxN) = A(MxK)*BT(NxK)^T, BM=128 BN=128 BK=64, 256 thr ======
template <int EPI>
__global__ __launch_bounds__(256, 2) void gemm2p_k(const unsigned short* __restrict__ A,
                                                   const unsigned short* __restrict__ BT,
                                                   unsigned short* __restrict__ Cbf,
                                                   float* __restrict__ Cf,
                                                   const float* __restrict__ resid,
                                                   int M, int N, int K, int nbx) {
  __shared__ __align__(1024) unsigned short lds[32768];  // A[2buf][2half][4096] | B same, 64KB
  const int t = threadIdx.x, w = t >> 6, l = t & 63;
  const int l15 = l & 15, lhi = l >> 4;
  const int wm = w >> 1, wn = w & 1;

  const int nwg = gridDim.x, per = nwg >> 3;
  const int bid = blockIdx.x;
  const int swz = (bid & 7) * per + (bid >> 3);  // XCD-contiguous (nwg % 8 == 0)
  const int by = swz / nbx, bx = swz % nbx;
  const int m0 = by * 128, n0 = bx * 128;

  const unsigned short *sAl0, *sAl1, *sAh0, *sAh1, *sBl0, *sBl1, *sBh0, *sBh1;
  {
    const int c = w, u = t & 63, r16 = u >> 2, jj = u & 3;
    const int xr = (r16 >> 1) & 3;
    const int rowL = (c >> 1) * 16 + r16, kL = (c & 1) * 32 + (jj ^ xr) * 8;
    const int rowH = ((c + 4) >> 1) * 16 + r16, kH = ((c + 4) & 1) * 32 + (jj ^ xr) * 8;
    sAl0 = A + (size_t)(m0 + rowL) * K + kL;
    sAl1 = A + (size_t)(m0 + rowH) * K + kH;
    sAh0 = A + (size_t)(m0 + 64 + rowL) * K + kL;
    sAh1 = A + (size_t)(m0 + 64 + rowH) * K + kH;
    sBl0 = BT + (size_t)(n0 + rowL) * K + kL;
    sBl1 = BT + (size_t)(n0 + rowH) * K + kH;
    sBh0 = BT + (size_t)(n0 + 64 + rowL) * K + kL;
    sBh1 = BT + (size_t)(n0 + 64 + rowH) * K + kH;
  }
  const int tail = l15 * 64 + ((lhi ^ ((l15 >> 1) & 3))) * 16;
  int aro[2][2], bro[2][2];
#pragma unroll
  for (int mi = 0; mi < 2; ++mi)
#pragma unroll
    for (int ks = 0; ks < 2; ++ks) aro[mi][ks] = ((wm * 2 + mi) * 2 + ks) * 1024 + tail;
#pragma unroll
  for (int ni = 0; ni < 2; ++ni)
#pragma unroll
    for (int ks = 0; ks < 2; ++ks) bro[ni][ks] = ((wn * 2 + ni) * 2 + ks) * 1024 + tail;

  floatx4 acc[4][4];
#pragma unroll
  for (int i = 0; i < 4; ++i)
#pragma unroll
    for (int j = 0; j < 4; ++j)
#pragma unroll
      for (int r = 0; r < 4; ++r) acc[i][j][r] = 0.f;

#define STAGE(dbuf, ko)                                                        \
  do {                                                                         \
    gload_lds16(sAl0 + (ko), &lds[(dbuf) * 8192 + w * 512]);                   \
    gload_lds16(sAl1 + (ko), &lds[(dbuf) * 8192 + 2048 + w * 512]);            \
    gload_lds16(sAh0 + (ko), &lds[(dbuf) * 8192 + 4096 + w * 512]);            \
    gload_lds16(sAh1 + (ko), &lds[(dbuf) * 8192 + 4096 + 2048 + w * 512]);     \
    gload_lds16(sBl0 + (ko), &lds[16384 + (dbuf) * 8192 + w * 512]);           \
    gload_lds16(sBl1 + (ko), &lds[16384 + (dbuf) * 8192 + 2048 + w * 512]);    \
  } while (0)
#define STAGE_BH(dbuf, ko)                                                     \
  do {                                                                         \
    gload_lds16(sBh0 + (ko), &lds[16384 + (dbuf) * 8192 + 4096 + w * 512]);    \
    gload_lds16(sBh1 + (ko), &lds[16384 + (dbuf) * 8192 + 4096 + 2048 + w * 512]); \
  } while (0)

  STAGE(0, 0);
  STAGE_BH(0, 0);
  asm volatile("s_waitcnt vmcnt(2)" ::: "memory");
  __builtin_amdgcn_s_barrier();
  __builtin_amdgcn_sched_barrier(0);

  const int nt = K >> 6;
  const char* ldsc = (const char*)lds;
  for (int kt = 0; kt < nt; ++kt) {
    const int d = kt & 1, dn = d ^ 1;
    const bool pf = (kt + 1 < nt);
    const int ko1 = (kt + 1) * 64;
    const int aB = d * 16384;          // A buf byte base
    const int bB = 32768 + d * 16384;  // B buf byte base
    short8 af[2][2][2], bf[2][2];      // af[qm][mi][ks]

    // ---- P1: qn=0. Read all A + B-lo; issue 6 next-tile loads. ----
#pragma unroll
    for (int qm = 0; qm < 2; ++qm)
#pragma unroll
      for (int mi = 0; mi < 2; ++mi)
#pragma unroll
        for (int ks = 0; ks < 2; ++ks)
          af[qm][mi][ks] = *(const short8*)(ldsc + aB + qm * 8192 + aro[mi][ks]);
#pragma unroll
    for (int ni = 0; ni < 2; ++ni)
#pragma unroll
      for (int ks = 0; ks < 2; ++ks)
        bf[ni][ks] = *(const short8*)(ldsc + bB + bro[ni][ks]);
    if (pf) STAGE(dn, ko1);
    __builtin_amdgcn_s_barrier();
    __builtin_amdgcn_sched_barrier(0);
    __builtin_amdgcn_s_setprio(1);
#pragma unroll
    for (int qm = 0; qm < 2; ++qm)
#pragma unroll
      for (int mi = 0; mi < 2; ++mi)
#pragma unroll
        for (int ni = 0; ni < 2; ++ni)
#pragma unroll
          for (int ks = 0; ks < 2; ++ks)
            acc[qm * 2 + mi][ni] = __builtin_amdgcn_mfma_f32_16x16x32_bf16(
                af[qm][mi][ks], bf[ni][ks], acc[qm * 2 + mi][ni], 0, 0, 0);
    __builtin_amdgcn_s_setprio(0);
    if (pf) { asm volatile("s_waitcnt vmcnt(6)" ::: "memory"); }  // retire Bhi(kt)
    else    { asm volatile("s_waitcnt vmcnt(0)" ::: "memory"); }  // last tile: drain
    __builtin_amdgcn_s_barrier();
    __builtin_amdgcn_sched_barrier(0);

    // ---- P2: qn=1. Read B-hi (byte offset 8192 = half h=1); reuse af; issue 2 loads. ----
#pragma unroll
    for (int ni = 0; ni < 2; ++ni)
#pragma unroll
      for (int ks = 0; ks < 2; ++ks)
        bf[ni][ks] = *(const short8*)(ldsc + bB + 8192 + bro[ni][ks]);
    if (pf) STAGE_BH(dn, ko1);
    __builtin_amdgcn_s_barrier();
    __builtin_amdgcn_sched_barrier(0);
    __builtin_amdgcn_s_setprio(1);
#pragma unroll
    for (int qm = 0; qm < 2; ++qm)
#pragma unroll
      for (int mi = 0; mi < 2; ++mi)
#pragma unroll
        for (int ni = 0; ni < 2; ++ni)
#pragma unroll
          for (int ks = 0; ks < 2; ++ks)
            acc[qm * 2 + mi][2 + ni] = __builtin_amdgcn_mfma_f32_16x16x32_bf16(
                af[qm][mi][ks], bf[ni][ks], acc[qm * 2 + mi][2 + ni], 0, 0, 0);
    __builtin_amdgcn_s_setprio(0);
    if (pf) { asm volatile("s_waitcnt vmcnt(2)" ::: "memory"); }  // retire A+Blo(kt+1)
    __builtin_amdgcn_s_barrier();
    __builtin_amdgcn_sched_barrier(0);
  }
#undef STAGE
#undef STAGE_BH

  // ---- epilogue ----
#pragma unroll
  for (int qm = 0; qm < 2; ++qm)
#pragma unroll
    for (int mi = 0; mi < 2; ++mi)
#pragma unroll
      for (int qn = 0; qn < 2; ++qn)
#pragma unroll
        for (int ni = 0; ni < 2; ++ni)
#pragma unroll
          for (int r = 0; r < 4; ++r) {
            const int row = m0 + qm * 64 + wm * 32 + mi * 16 + lhi * 4 + r;
            const int col = n0 + qn * 64 + wn * 32 + ni * 16 + l15;
            const size_t idx = (size_t)row * N + col;
            const float v = acc[qm * 2 + mi][qn * 2 + ni][r];
            if (EPI == 0) Cbf[idx] = f2bf(v);
            else Cf[idx] = v + resid[idx];
          }
}

// ======== Flash attention (R12-exact math/memory path) + T5 setprio ========
__global__ __launch_bounds__(256, 2) void attn3_k(const unsigned short* __restrict__ Q,
                                                  const unsigned short* __restrict__ Kall,
                                                  const unsigned short* __restrict__ VT,
                                                  unsigned short* __restrict__ O) {
  __shared__ unsigned short Ks[2][8192];
  __shared__ unsigned short Vs[2][8192];
  __shared__ unsigned short ot[4][32][40];
  const int bid = blockIdx.x;
  const int swz = (bid & 7) * 64 + (bid >> 3);
  const int qt = swz & 15, hk = (swz >> 4) & 7, b = swz >> 7;
  const int t = threadIdx.x, w = t >> 6, l = t & 63;
  const int q5 = l & 31, h = l >> 5;

  const int nq = qt * 32 + w * 8 + (q5 >> 2);
  const int g = q5 & 3;
  const int qpos = CACHE_C + nq;

  const unsigned short* Kb = Kall + (size_t)(b * 8 + hk) * TOTAL_C * 128;
  const unsigned short* Vb = VT + (size_t)(b * 8 + hk) * 128 * TOTAL_C;

  const unsigned short* ksrc[4];
  const unsigned short* vsrc[4];
#pragma unroll
  for (int j = 0; j < 4; ++j) {
    const int c = w * 256 + j * 64 + l;
    const int sck = c ^ ((c >> 4) & 7);
    ksrc[j] = Kb + sck * 8;
    const int scv = c ^ ((c >> 3) & 7);
    vsrc[j] = Vb + (size_t)(c >> 3) * TOTAL_C + (scv & 7) * 8;
  }

  const int xmask = (q5 & 7) << 4;
  int kb_[8], vb_[4];
#pragma unroll
  for (int ks = 0; ks < 8; ++ks) kb_[ks] = q5 * 256 + ((ks * 32 + h * 16) ^ xmask);
#pragma unroll
  for (int f = 0; f < 4; ++f) vb_[f] = q5 * 128 + ((f * 32 + h * 16) ^ xmask);

  short8 qf[8];
  {
    const unsigned short* qrow =
        Q + (size_t)(b * 512 + nq) * 4096 + (hk * 4 + g) * 128 + h * 8;
#pragma unroll
    for (int ks = 0; ks < 8; ++ks) qf[ks] = *(const short8*)(qrow + ks * 16);
  }

  f32x16 oacc[4];
#pragma unroll
  for (int d = 0; d < 4; ++d)
#pragma unroll
    for (int r = 0; r < 16; ++r) oacc[d][r] = 0.f;
  float m = -1e30f, lsum = 0.f;

  const int nblk = ((CACHE_C + qt * 32 + 31) >> 6) + 1;

#pragma unroll
  for (int j = 0; j < 4; ++j) gload_lds16(ksrc[j], &Ks[0][w * 2048 + j * 512]);
#pragma unroll
  for (int j = 0; j < 4; ++j) gload_lds16(vsrc[j], &Vs[0][w * 2048 + j * 512]);

  for (int sb = 0; sb < nblk; ++sb) {
    __syncthreads();
    if (sb + 1 < nblk) {
      const int p1 = (sb + 1) & 1;
#pragma unroll
      for (int j = 0; j < 4; ++j)
        gload_lds16(ksrc[j] + (sb + 1) * 8192, &Ks[p1][w * 2048 + j * 512]);
#pragma unroll
      for (int j = 0; j < 4; ++j)
        gload_lds16(vsrc[j] + (sb + 1) * 64, &Vs[p1][w * 2048 + j * 512]);
      __builtin_amdgcn_sched_barrier(0);
    }
    const int s0 = sb << 6;
    const char* kp = (const char*)&Ks[sb & 1][0];
    const char* vp = (const char*)&Vs[sb & 1][0];

    f32x16 sa0, sa1;
#pragma unroll
    for (int r = 0; r < 16; ++r) { sa0[r] = 0.f; sa1[r] = 0.f; }
    __builtin_amdgcn_s_setprio(1);
#pragma unroll
    for (int ks = 0; ks < 8; ++ks) {
      short8 k0 = *(const short8*)(kp + kb_[ks]);
      short8 k1 = *(const short8*)(kp + kb_[ks] + 8192);
      sa0 = __builtin_amdgcn_mfma_f32_32x32x16_bf16(k0, qf[ks], sa0, 0, 0, 0);
      sa1 = __builtin_amdgcn_mfma_f32_32x32x16_bf16(k1, qf[ks], sa1, 0, 0, 0);
    }
    __builtin_amdgcn_s_setprio(0);
    if (sb == nblk - 1) {
#pragma unroll
      for (int r = 0; r < 16; ++r) {
        const int sg = s0 + ((r & 3) + 8 * (r >> 2) + 4 * h);
        if (sg > qpos) sa0[r] = -1e30f;
        if (sg + 32 > qpos) sa1[r] = -1e30f;
      }
    }
    // ---- row max (max3-foldable nesting) ----
    float m8[8];
#pragma unroll
    for (int i = 0; i < 8; ++i)
      m8[i] = fmaxf(fmaxf(fmaxf(sa0[i], sa0[i + 8]), sa1[i]), sa1[i + 8]);
    float t0 = fmaxf(fmaxf(m8[0], m8[1]), m8[2]);
    float t1 = fmaxf(fmaxf(m8[3], m8[4]), m8[5]);
    float t2 = fmaxf(m8[6], m8[7]);
    const float ml = fmaxf(fmaxf(t0, t1), t2);
    const float pmax = fmaxf(ml, __shfl_xor(ml, 32));
    if (__any(pmax > m)) {
      const float mn = fmaxf(m, pmax);
      const float sco = __builtin_amdgcn_exp2f(m - mn);
      m = mn;
      lsum *= sco;
#pragma unroll
      for (int d = 0; d < 4; ++d)
#pragma unroll
        for (int r = 0; r < 16; ++r) oacc[d][r] *= sco;
    }
    unsigned pk[16];
    float s16[16];
#pragma unroll
    for (int i = 0; i < 8; ++i) {
      const float a0 = __builtin_amdgcn_exp2f(sa0[2 * i] - m);
      const float a1 = __builtin_amdgcn_exp2f(sa0[2 * i + 1] - m);
      const float b0 = __builtin_amdgcn_exp2f(sa1[2 * i] - m);
      const float b1 = __builtin_amdgcn_exp2f(sa1[2 * i + 1] - m);
      pk[i] = pack_trunc(a0, a1);
      pk[i + 8] = pack_trunc(b0, b1);
      s16[i] = a0 + a1;
      s16[i + 8] = b0 + b1;
    }
#pragma unroll
    for (int st = 8; st >= 1; st >>= 1)
#pragma unroll
      for (int i = 0; i < st; ++i) s16[i] += s16[i + st];
    lsum += s16[0];
    // ---- P exchange via permlane32_swap (VALU, no DS) + PV ----
    __builtin_amdgcn_s_setprio(1);
#pragma unroll
    for (int f = 0; f < 4; ++f) {
      uint2v s1 = __builtin_amdgcn_permlane32_swap(pk[4 * f + 0], pk[4 * f + 2], false, false);
      uint2v s2 = __builtin_amdgcn_permlane32_swap(pk[4 * f + 1], pk[4 * f + 3], false, false);
      union { int4 i4; short8 s8; } fr;
      fr.i4.x = (int)s1[0];
      fr.i4.y = (int)s2[0];
      fr.i4.z = (int)s1[1];
      fr.i4.w = (int)s2[1];
#pragma unroll
      for (int d = 0; d < 4; ++d) {
        short8 vf = *(const short8*)(vp + vb_[f] + d * 4096);
        oacc[d] = __builtin_amdgcn_mfma_f32_32x32x16_bf16(vf, fr.s8, oacc[d], 0, 0, 0);
      }
    }
    __builtin_amdgcn_s_setprio(0);
  }

  lsum += __shfl_xor(lsum, 32);
  const float inv = 1.f / lsum;
#pragma unroll
  for (int db = 0; db < 4; ++db) {
    __syncthreads();
#pragma unroll
    for (int r = 0; r < 16; r += 2) {
      const float v0 = oacc[db][r] * inv;
      const float v1 = oacc[db][r + 1] * inv;
      const int dloc = (r & 3) + 8 * (r >> 2) + 4 * h;
      *(unsigned*)&ot[w][q5][dloc] = pack_bf16(v0, v1);
    }
    __syncthreads();
    const int qr_ = l >> 1, half = l & 1;
    const short8 ov0 = *(const short8*)&ot[w][qr_][half * 16];
    const short8 ov1 = *(const short8*)&ot[w][qr_][half * 16 + 8];
    const int n2 = qt * 32 + w * 8 + (qr_ >> 2), g2 = qr_ & 3;
    const size_t ob = (size_t)(b * 512 + n2) * 4096 + (hk * 4 + g2) * 128 + db * 32 + half * 16;
    *(short8*)&O[ob] = ov0;
    *(short8*)&O[ob + 8] = ov1;
  }
}

extern "C" void kernel_launch(void* const* d_in, const int* in_sizes, int n_in,
                              void* d_out, int out_size, void* d_ws, size_t ws_size,
                              hipStream_t stream) {
  const float* x = (const float*)d_in[0];
  const float* cosb = (const float*)d_in[1];
  const float* sinb = (const float*)d_in[2];
  const float* lnw = (const float*)d_in[3];
  const float* wq = (const float*)d_in[4];
  const float* wk = (const float*)d_in[5];
  const float* wv = (const float*)d_in[6];
  const float* wo = (const float*)d_in[7];
  const float* kcache = (const float*)d_in[8];
  const float* vcache = (const float*)d_in[9];
  float* out = (float*)d_out;
  char* ws = (char*)d_ws;

  unsigned short* hn    = (unsigned short*)(ws + 0);          // 16.8 MB
  unsigned short* wqkvT = (unsigned short*)(ws + 16777216);   // 50.3 MB
  unsigned short* qkv   = (unsigned short*)(ws + 67108864);   // 25.2 MB
  unsigned short* qrope = (unsigned short*)(ws + 92274688);   // 16.8 MB
  unsigned short* Kall  = (unsigned short*)(ws + 109051904);  // 37.75 MB
  unsigned short* VallT = (unsigned short*)(ws + 146800640);  // 37.75 MB
  unsigned short* attno = hn;     // alias: hn dead after QKV GEMM
  unsigned short* woT   = wqkvT;  // alias: wqkvT dead after QKV GEMM

  rmsnorm_k<<<2048, 256, 0, stream>>>(x, lnw, hn);
  build_wqkvT_k<<<dim3(192, 128), 256, 0, stream>>>(wq, wk, wv, wqkvT);
  gemm2p_k<0><<<768, 256, 0, stream>>>(hn, wqkvT, qkv, nullptr, nullptr, 2048, 6144, 4096, 48);
  rope_k<<<2048, 256, 0, stream>>>(qkv, cosb, sinb, qrope, Kall);
  transpose_u16_k<<<dim3(32, 16, 4), 256, 0, stream>>>(qkv + 5120, 512L * QKV_N, QKV_N,
                                                       VallT + CACHE_C, 4718592L, TOTAL_C);
  cvt_kcache_k<<<16384, 256, 0, stream>>>(kcache, Kall);
  transpose_cvt_k<<<dim3(4, 128, 32), 256, 0, stream>>>(vcache, 4718592L, 128L, 1024,
                                                        VallT, 589824L, TOTAL_C);
  attn3_k<<<512, 256, 0, stream>>>(qrope, Kall, VallT, attno);
  transpose_cvt_k<<<dim3(128, 128, 1), 256, 0, stream>>>(wo, 0L, 0L, 4096, woT, 0L, 4096);
  gemm2p_k<1><<<512, 256, 0, stream>>>(attno, woT, nullptr, out, x, 2048, 4096, 4096, 32);
}

// Round 15
// 492.794 us; speedup vs baseline: 1.0188x; 1.0188x over previous
//
#include <hip/hip_runtime.h>
#include <hip/hip_bf16.h>

typedef __attribute__((ext_vector_type(8))) short short8;
typedef __attribute__((ext_vector_type(4))) float floatx4;
typedef __attribute__((ext_vector_type(16))) float f32x16;
typedef __attribute__((ext_vector_type(2))) unsigned uint2v;

#define B_C 4
#define NEW_C 512
#define CACHE_C 4096
#define TOTAL_C 4608
#define H_C 32
#define HKV_C 8
#define D_C 128
#define HID_C 4096
#define QKV_N 6144

__device__ __forceinline__ unsigned short f2bf(float f) {
  union { float f; unsigned u; } v; v.f = f;
  unsigned r = v.u + 0x7FFFu + ((v.u >> 16) & 1u);
  return (unsigned short)(r >> 16);
}
__device__ __forceinline__ float bf2f(unsigned short h) {
  union { unsigned u; float f; } v; v.u = ((unsigned)h) << 16; return v.f;
}
__device__ __forceinline__ unsigned pack_bf16(float lo, float hi) {
  return ((unsigned)f2bf(hi) << 16) | (unsigned)f2bf(lo);
}
// single v_perm_b32: bf16 pair via truncation (RTZ).
__device__ __forceinline__ unsigned pack_trunc(float lo, float hi) {
  union { float f; unsigned u; } a, b;
  a.f = lo; b.f = hi;
  return __builtin_amdgcn_perm(b.u, a.u, 0x07060302u);
}
__device__ __forceinline__ void gload_lds16(const unsigned short* g, unsigned short* lds) {
  __builtin_amdgcn_global_load_lds(
      (const __attribute__((address_space(1))) unsigned int*)g,
      (__attribute__((address_space(3))) unsigned int*)lds, 16, 0, 0);
}

// ---------------- RMSNorm: x f32 (2048x4096) -> hn bf16 ----------------
__global__ __launch_bounds__(256) void rmsnorm_k(const float* __restrict__ x,
                                                 const float* __restrict__ g,
                                                 unsigned short* __restrict__ hn) {
  const int row = blockIdx.x;
  const int t = threadIdx.x;
  const float4* xr = (const float4*)(x + (size_t)row * 4096);
  float4 v[4];
  float ss = 0.f;
#pragma unroll
  for (int i = 0; i < 4; ++i) {
    v[i] = xr[t + i * 256];
    ss += v[i].x * v[i].x + v[i].y * v[i].y + v[i].z * v[i].z + v[i].w * v[i].w;
  }
#pragma unroll
  for (int m = 1; m < 64; m <<= 1) ss += __shfl_xor(ss, m);
  __shared__ float red[4];
  if ((t & 63) == 0) red[t >> 6] = ss;
  __syncthreads();
  ss = red[0] + red[1] + red[2] + red[3];
  const float inv = rsqrtf(ss * (1.f / 4096.f) + 1e-6f);
  const float4* gw = (const float4*)g;
#pragma unroll
  for (int i = 0; i < 4; ++i) {
    float4 w4 = gw[t + i * 256];
    ushort4 o;
    o.x = f2bf(v[i].x * inv * w4.x);
    o.y = f2bf(v[i].y * inv * w4.y);
    o.z = f2bf(v[i].z * inv * w4.z);
    o.w = f2bf(v[i].w * inv * w4.w);
    *(ushort4*)&hn[(size_t)row * 4096 + (t + i * 256) * 4] = o;
  }
}

// ---- build wqkvT bf16 (6144 x 4096): wqkvT[n][k] = {wq|wk|wv}[k][n] ----
__global__ __launch_bounds__(256) void build_wqkvT_k(const float* __restrict__ wq,
                                                     const float* __restrict__ wk,
                                                     const float* __restrict__ wv,
                                                     unsigned short* __restrict__ out) {
  __shared__ float tile[32][33];
  const int n0 = blockIdx.x * 32, k0 = blockIdx.y * 32;
  const float* src; int ld, nc;
  if (n0 < 4096)      { src = wq; ld = 4096; nc = n0; }
  else if (n0 < 5120) { src = wk; ld = 1024; nc = n0 - 4096; }
  else                { src = wv; ld = 1024; nc = n0 - 5120; }
  const int t = threadIdx.x, r = t >> 3, cv = (t & 7) * 4;
  const float4 v = *(const float4*)&src[(size_t)(k0 + r) * ld + nc + cv];
  tile[r][cv + 0] = v.x; tile[r][cv + 1] = v.y; tile[r][cv + 2] = v.z; tile[r][cv + 3] = v.w;
  __syncthreads();
  ushort4 o;
  o.x = f2bf(tile[cv + 0][r]); o.y = f2bf(tile[cv + 1][r]);
  o.z = f2bf(tile[cv + 2][r]); o.w = f2bf(tile[cv + 3][r]);
  *(ushort4*)&out[(size_t)(n0 + r) * 4096 + k0 + cv] = o;
}

// ---- generic f32->bf16 32x32 transpose: dst[c][r] = src[r][c] ----
__global__ __launch_bounds__(256) void transpose_cvt_k(const float* __restrict__ src,
                                                       long sbs_hi, long sbs_lo, int sld,
                                                       unsigned short* __restrict__ dst,
                                                       long dbs, int dld) {
  __shared__ float tile[32][33];
  const int z = blockIdx.z;
  const long sb = (long)(z >> 3) * sbs_hi + (long)(z & 7) * sbs_lo;
  const long db = (long)z * dbs;
  const int r0 = blockIdx.y * 32, c0 = blockIdx.x * 32;
  const int t = threadIdx.x, r = t >> 3, cv = (t & 7) * 4;
  const float4 v = *(const float4*)&src[sb + (long)(r0 + r) * sld + c0 + cv];
  tile[r][cv + 0] = v.x; tile[r][cv + 1] = v.y; tile[r][cv + 2] = v.z; tile[r][cv + 3] = v.w;
  __syncthreads();
  ushort4 o;
  o.x = f2bf(tile[cv + 0][r]); o.y = f2bf(tile[cv + 1][r]);
  o.z = f2bf(tile[cv + 2][r]); o.w = f2bf(tile[cv + 3][r]);
  *(ushort4*)&dst[db + (long)(c0 + r) * dld + r0 + cv] = o;
}

// ---- u16 32x32 transpose (no convert): dst[c][r] = src[r][c] ----
__global__ __launch_bounds__(256) void transpose_u16_k(const unsigned short* __restrict__ src,
                                                       long sbs, int sld,
                                                       unsigned short* __restrict__ dst,
                                                       long dbs, int dld) {
  __shared__ unsigned short tile[32][36];
  const int z = blockIdx.z;
  const long sb = (long)z * sbs;
  const long db = (long)z * dbs;
  const int r0 = blockIdx.y * 32, c0 = blockIdx.x * 32;
  const int t = threadIdx.x, r = t >> 3, cv = (t & 7) * 4;
  const ushort4 v = *(const ushort4*)&src[sb + (long)(r0 + r) * sld + c0 + cv];
  tile[r][cv + 0] = v.x; tile[r][cv + 1] = v.y; tile[r][cv + 2] = v.z; tile[r][cv + 3] = v.w;
  __syncthreads();
  ushort4 o;
  o.x = tile[cv + 0][r]; o.y = tile[cv + 1][r]; o.z = tile[cv + 2][r]; o.w = tile[cv + 3][r];
  *(ushort4*)&dst[db + (long)(c0 + r) * dld + r0 + cv] = o;
}

// ---- k_cache f32 (B,TOTAL,HKV,D) s<CACHE -> K_all bf16 (B,HKV,TOTAL,D) ----
__global__ __launch_bounds__(256) void cvt_kcache_k(const float* __restrict__ kc,
                                                    unsigned short* __restrict__ Kall) {
  const long i = (long)blockIdx.x * 256 + threadIdx.x;  // over 4*8*4096*32 float4
  const long c = i & 31, s = (i >> 5) & 4095, h = (i >> 17) & 7, b = i >> 20;
  const float4 v = *(const float4*)&kc[((b * 4608 + s) * 8 + h) * 128 + c * 4];
  ushort4 o;
  o.x = f2bf(v.x); o.y = f2bf(v.y); o.z = f2bf(v.z); o.w = f2bf(v.w);
  *(ushort4*)&Kall[((b * 8 + h) * 4608L + s) * 128 + c * 4] = o;
}

// ---- RoPE: qkv bf16 row -> q_rope bf16 (PRE-SCALED by 1/sqrt(D)*log2e), K_all bf16 ----
__global__ __launch_bounds__(256) void rope_k(const unsigned short* __restrict__ qkv,
                                              const float* __restrict__ cosb,
                                              const float* __restrict__ sinb,
                                              unsigned short* __restrict__ qr,
                                              unsigned short* __restrict__ Kall) {
  const float SCL = 0.08838834764831845f * 1.4426950408889634f;  // 1/sqrt(128) * log2(e)
  const int row = blockIdx.x;
  const int b = row >> 9, n = row & 511;
  const unsigned short* src = qkv + (size_t)row * QKV_N;
  const float* cr = cosb + (size_t)row * 128;
  const float* sr = sinb + (size_t)row * 128;
  const int t = threadIdx.x;
#pragma unroll
  for (int i = 0; i < 8; ++i) {  // Q: 32 heads * 64 pairs
    int pid = t + i * 256;
    int hd = pid >> 6, d = pid & 63;
    int idx = hd * 128 + d;
    float a = bf2f(src[idx]), bb = bf2f(src[idx + 64]);
    float c0 = cr[d], s0 = sr[d], c1 = cr[d + 64], s1 = sr[d + 64];
    qr[(size_t)row * 4096 + idx] = f2bf((a * c0 - bb * s0) * SCL);
    qr[(size_t)row * 4096 + idx + 64] = f2bf((bb * c1 + a * s1) * SCL);
  }
#pragma unroll
  for (int i = 0; i < 2; ++i) {  // K: 8 heads * 64 pairs
    int pid = t + i * 256;
    int hd = pid >> 6, d = pid & 63;
    float a = bf2f(src[4096 + hd * 128 + d]), bb = bf2f(src[4096 + hd * 128 + d + 64]);
    float c0 = cr[d], s0 = sr[d], c1 = cr[d + 64], s1 = sr[d + 64];
    long kb = ((long)(b * 8 + hd) * TOTAL_C + CACHE_C + n) * 128 + d;
    Kall[kb] = f2bf(a * c0 - bb * s0);
    Kall[kb + 64] = f2bf(bb * c1 + a * s1);
  }
}

// ====== GEMM 2-phase: C(MxN) = A(MxK)*BT(NxK)^T, BM=128 BN=128 BK=64, 256 thr ======
template <int EPI>
__global__ __launch_bounds__(256, 2) void gemm2p_k(const unsigned short* __restrict__ A,
                                                   const unsigned short* __restrict__ BT,
                                                   unsigned short* __restrict__ Cbf,
                                                   float* __restrict__ Cf,
                                                   const float* __restrict__ resid,
                                                   int M, int N, int K, int nbx) {
  __shared__ __align__(1024) unsigned short lds[32768];  // A[2buf][2half][4096] | B same, 64KB
  const int t = threadIdx.x, w = t >> 6, l = t & 63;
  const int l15 = l & 15, lhi = l >> 4;
  const int wm = w >> 1, wn = w & 1;

  const int nwg = gridDim.x, per = nwg >> 3;
  const int bid = blockIdx.x;
  const int swz = (bid & 7) * per + (bid >> 3);  // XCD-contiguous (nwg % 8 == 0)
  const int by = swz / nbx, bx = swz % nbx;
  const int m0 = by * 128, n0 = bx * 128;

  const unsigned short *sAl0, *sAl1, *sAh0, *sAh1, *sBl0, *sBl1, *sBh0, *sBh1;
  {
    const int c = w, u = t & 63, r16 = u >> 2, jj = u & 3;
    const int xr = (r16 >> 1) & 3;
    const int rowL = (c >> 1) * 16 + r16, kL = (c & 1) * 32 + (jj ^ xr) * 8;
    const int rowH = ((c + 4) >> 1) * 16 + r16, kH = ((c + 4) & 1) * 32 + (jj ^ xr) * 8;
    sAl0 = A + (size_t)(m0 + rowL) * K + kL;
    sAl1 = A + (size_t)(m0 + rowH) * K + kH;
    sAh0 = A + (size_t)(m0 + 64 + rowL) * K + kL;
    sAh1 = A + (size_t)(m0 + 64 + rowH) * K + kH;
    sBl0 = BT + (size_t)(n0 + rowL) * K + kL;
    sBl1 = BT + (size_t)(n0 + rowH) * K + kH;
    sBh0 = BT + (size_t)(n0 + 64 + rowL) * K + kL;
    sBh1 = BT + (size_t)(n0 + 64 + rowH) * K + kH;
  }
  const int tail = l15 * 64 + ((lhi ^ ((l15 >> 1) & 3))) * 16;
  int aro[2][2], bro[2][2];
#pragma unroll
  for (int mi = 0; mi < 2; ++mi)
#pragma unroll
    for (int ks = 0; ks < 2; ++ks) aro[mi][ks] = ((wm * 2 + mi) * 2 + ks) * 1024 + tail;
#pragma unroll
  for (int ni = 0; ni < 2; ++ni)
#pragma unroll
    for (int ks = 0; ks < 2; ++ks) bro[ni][ks] = ((wn * 2 + ni) * 2 + ks) * 1024 + tail;

  floatx4 acc[4][4];
#pragma unroll
  for (int i = 0; i < 4; ++i)
#pragma unroll
    for (int j = 0; j < 4; ++j)
#pragma unroll
      for (int r = 0; r < 4; ++r) acc[i][j][r] = 0.f;

#define STAGE(dbuf, ko)                                                        \
  do {                                                                         \
    gload_lds16(sAl0 + (ko), &lds[(dbuf) * 8192 + w * 512]);                   \
    gload_lds16(sAl1 + (ko), &lds[(dbuf) * 8192 + 2048 + w * 512]);            \
    gload_lds16(sAh0 + (ko), &lds[(dbuf) * 8192 + 4096 + w * 512]);            \
    gload_lds16(sAh1 + (ko), &lds[(dbuf) * 8192 + 4096 + 2048 + w * 512]);     \
    gload_lds16(sBl0 + (ko), &lds[16384 + (dbuf) * 8192 + w * 512]);           \
    gload_lds16(sBl1 + (ko), &lds[16384 + (dbuf) * 8192 + 2048 + w * 512]);    \
  } while (0)
#define STAGE_BH(dbuf, ko)                                                     \
  do {                                                                         \
    gload_lds16(sBh0 + (ko), &lds[16384 + (dbuf) * 8192 + 4096 + w * 512]);    \
    gload_lds16(sBh1 + (ko), &lds[16384 + (dbuf) * 8192 + 4096 + 2048 + w * 512]); \
  } while (0)

  STAGE(0, 0);
  STAGE_BH(0, 0);
  asm volatile("s_waitcnt vmcnt(2)" ::: "memory");
  __builtin_amdgcn_s_barrier();
  __builtin_amdgcn_sched_barrier(0);

  const int nt = K >> 6;
  const char* ldsc = (const char*)lds;
  for (int kt = 0; kt < nt; ++kt) {
    const int d = kt & 1, dn = d ^ 1;
    const bool pf = (kt + 1 < nt);
    const int ko1 = (kt + 1) * 64;
    const int aB = d * 16384;          // A buf byte base
    const int bB = 32768 + d * 16384;  // B buf byte base
    short8 af[2][2][2], bf[2][2];      // af[qm][mi][ks]

    // ---- P1: qn=0. Read all A + B-lo; issue 6 next-tile loads. ----
#pragma unroll
    for (int qm = 0; qm < 2; ++qm)
#pragma unroll
      for (int mi = 0; mi < 2; ++mi)
#pragma unroll
        for (int ks = 0; ks < 2; ++ks)
          af[qm][mi][ks] = *(const short8*)(ldsc + aB + qm * 8192 + aro[mi][ks]);
#pragma unroll
    for (int ni = 0; ni < 2; ++ni)
#pragma unroll
      for (int ks = 0; ks < 2; ++ks)
        bf[ni][ks] = *(const short8*)(ldsc + bB + bro[ni][ks]);
    if (pf) STAGE(dn, ko1);
    __builtin_amdgcn_s_barrier();
    __builtin_amdgcn_sched_barrier(0);
    __builtin_amdgcn_s_setprio(1);
#pragma unroll
    for (int qm = 0; qm < 2; ++qm)
#pragma unroll
      for (int mi = 0; mi < 2; ++mi)
#pragma unroll
        for (int ni = 0; ni < 2; ++ni)
#pragma unroll
          for (int ks = 0; ks < 2; ++ks)
            acc[qm * 2 + mi][ni] = __builtin_amdgcn_mfma_f32_16x16x32_bf16(
                af[qm][mi][ks], bf[ni][ks], acc[qm * 2 + mi][ni], 0, 0, 0);
    __builtin_amdgcn_s_setprio(0);
    if (pf) { asm volatile("s_waitcnt vmcnt(6)" ::: "memory"); }  // retire Bhi(kt)
    else    { asm volatile("s_waitcnt vmcnt(0)" ::: "memory"); }  // last tile: drain
    __builtin_amdgcn_s_barrier();
    __builtin_amdgcn_sched_barrier(0);

    // ---- P2: qn=1. Read B-hi (byte offset 8192 = half h=1); reuse af; issue 2 loads. ----
#pragma unroll
    for (int ni = 0; ni < 2; ++ni)
#pragma unroll
      for (int ks = 0; ks < 2; ++ks)
        bf[ni][ks] = *(const short8*)(ldsc + bB + 8192 + bro[ni][ks]);
    if (pf) STAGE_BH(dn, ko1);
    __builtin_amdgcn_s_barrier();
    __builtin_amdgcn_sched_barrier(0);
    __builtin_amdgcn_s_setprio(1);
#pragma unroll
    for (int qm = 0; qm < 2; ++qm)
#pragma unroll
      for (int mi = 0; mi < 2; ++mi)
#pragma unroll
        for (int ni = 0; ni < 2; ++ni)
#pragma unroll
          for (int ks = 0; ks < 2; ++ks)
            acc[qm * 2 + mi][2 + ni] = __builtin_amdgcn_mfma_f32_16x16x32_bf16(
                af[qm][mi][ks], bf[ni][ks], acc[qm * 2 + mi][2 + ni], 0, 0, 0);
    __builtin_amdgcn_s_setprio(0);
    if (pf) { asm volatile("s_waitcnt vmcnt(2)" ::: "memory"); }  // retire A+Blo(kt+1)
    __builtin_amdgcn_s_barrier();
    __builtin_amdgcn_sched_barrier(0);
  }
#undef STAGE
#undef STAGE_BH

  // ---- epilogue ----
#pragma unroll
  for (int qm = 0; qm < 2; ++qm)
#pragma unroll
    for (int mi = 0; mi < 2; ++mi)
#pragma unroll
      for (int qn = 0; qn < 2; ++qn)
#pragma unroll
        for (int ni = 0; ni < 2; ++ni)
#pragma unroll
          for (int r = 0; r < 4; ++r) {
            const int row = m0 + qm * 64 + wm * 32 + mi * 16 + lhi * 4 + r;
            const int col = n0 + qn * 64 + wn * 32 + ni * 16 + l15;
            const size_t idx = (size_t)row * N + col;
            const float v = acc[qm * 2 + mi][qn * 2 + ni][r];
            if (EPI == 0) Cbf[idx] = f2bf(v);
            else Cf[idx] = v + resid[idx];
          }
}

// ======== Flash attention (R12-exact: permlane P-exchange, max3 row-max, no setprio) ========
__global__ __launch_bounds__(256, 2) void attn3_k(const unsigned short* __restrict__ Q,
                                                  const unsigned short* __restrict__ Kall,
                                                  const unsigned short* __restrict__ VT,
                                                  unsigned short* __restrict__ O) {
  __shared__ unsigned short Ks[2][8192];
  __shared__ unsigned short Vs[2][8192];
  __shared__ unsigned short ot[4][32][40];
  const int bid = blockIdx.x;
  const int swz = (bid & 7) * 64 + (bid >> 3);
  const int qt = swz & 15, hk = (swz >> 4) & 7, b = swz >> 7;
  const int t = threadIdx.x, w = t >> 6, l = t & 63;
  const int q5 = l & 31, h = l >> 5;

  const int nq = qt * 32 + w * 8 + (q5 >> 2);
  const int g = q5 & 3;
  const int qpos = CACHE_C + nq;

  const unsigned short* Kb = Kall + (size_t)(b * 8 + hk) * TOTAL_C * 128;
  const unsigned short* Vb = VT + (size_t)(b * 8 + hk) * 128 * TOTAL_C;

  const unsigned short* ksrc[4];
  const unsigned short* vsrc[4];
#pragma unroll
  for (int j = 0; j < 4; ++j) {
    const int c = w * 256 + j * 64 + l;
    const int sck = c ^ ((c >> 4) & 7);
    ksrc[j] = Kb + sck * 8;
    const int scv = c ^ ((c >> 3) & 7);
    vsrc[j] = Vb + (size_t)(c >> 3) * TOTAL_C + (scv & 7) * 8;
  }

  const int xmask = (q5 & 7) << 4;
  int kb_[8], vb_[4];
#pragma unroll
  for (int ks = 0; ks < 8; ++ks) kb_[ks] = q5 * 256 + ((ks * 32 + h * 16) ^ xmask);
#pragma unroll
  for (int f = 0; f < 4; ++f) vb_[f] = q5 * 128 + ((f * 32 + h * 16) ^ xmask);

  short8 qf[8];
  {
    const unsigned short* qrow =
        Q + (size_t)(b * 512 + nq) * 4096 + (hk * 4 + g) * 128 + h * 8;
#pragma unroll
    for (int ks = 0; ks < 8; ++ks) qf[ks] = *(const short8*)(qrow + ks * 16);
  }

  f32x16 oacc[4];
#pragma unroll
  for (int d = 0; d < 4; ++d)
#pragma unroll
    for (int r = 0; r < 16; ++r) oacc[d][r] = 0.f;
  float m = -1e30f, lsum = 0.f;

  const int nblk = ((CACHE_C + qt * 32 + 31) >> 6) + 1;

#pragma unroll
  for (int j = 0; j < 4; ++j) gload_lds16(ksrc[j], &Ks[0][w * 2048 + j * 512]);
#pragma unroll
  for (int j = 0; j < 4; ++j) gload_lds16(vsrc[j], &Vs[0][w * 2048 + j * 512]);

  for (int sb = 0; sb < nblk; ++sb) {
    __syncthreads();
    if (sb + 1 < nblk) {
      const int p1 = (sb + 1) & 1;
#pragma unroll
      for (int j = 0; j < 4; ++j)
        gload_lds16(ksrc[j] + (sb + 1) * 8192, &Ks[p1][w * 2048 + j * 512]);
#pragma unroll
      for (int j = 0; j < 4; ++j)
        gload_lds16(vsrc[j] + (sb + 1) * 64, &Vs[p1][w * 2048 + j * 512]);
      __builtin_amdgcn_sched_barrier(0);
    }
    const int s0 = sb << 6;
    const char* kp = (const char*)&Ks[sb & 1][0];
    const char* vp = (const char*)&Vs[sb & 1][0];

    f32x16 sa0, sa1;
#pragma unroll
    for (int r = 0; r < 16; ++r) { sa0[r] = 0.f; sa1[r] = 0.f; }
#pragma unroll
    for (int ks = 0; ks < 8; ++ks) {
      short8 k0 = *(const short8*)(kp + kb_[ks]);
      short8 k1 = *(const short8*)(kp + kb_[ks] + 8192);
      sa0 = __builtin_amdgcn_mfma_f32_32x32x16_bf16(k0, qf[ks], sa0, 0, 0, 0);
      sa1 = __builtin_amdgcn_mfma_f32_32x32x16_bf16(k1, qf[ks], sa1, 0, 0, 0);
    }
    if (sb == nblk - 1) {
#pragma unroll
      for (int r = 0; r < 16; ++r) {
        const int sg = s0 + ((r & 3) + 8 * (r >> 2) + 4 * h);
        if (sg > qpos) sa0[r] = -1e30f;
        if (sg + 32 > qpos) sa1[r] = -1e30f;
      }
    }
    // ---- row max (max3-foldable nesting) ----
    float m8[8];
#pragma unroll
    for (int i = 0; i < 8; ++i)
      m8[i] = fmaxf(fmaxf(fmaxf(sa0[i], sa0[i + 8]), sa1[i]), sa1[i + 8]);
    float t0 = fmaxf(fmaxf(m8[0], m8[1]), m8[2]);
    float t1 = fmaxf(fmaxf(m8[3], m8[4]), m8[5]);
    float t2 = fmaxf(m8[6], m8[7]);
    const float ml = fmaxf(fmaxf(t0, t1), t2);
    const float pmax = fmaxf(ml, __shfl_xor(ml, 32));
    if (__any(pmax > m)) {
      const float mn = fmaxf(m, pmax);
      const float sco = __builtin_amdgcn_exp2f(m - mn);
      m = mn;
      lsum *= sco;
#pragma unroll
      for (int d = 0; d < 4; ++d)
#pragma unroll
        for (int r = 0; r < 16; ++r) oacc[d][r] *= sco;
    }
    unsigned pk[16];
    float s16[16];
#pragma unroll
    for (int i = 0; i < 8; ++i) {
      const float a0 = __builtin_amdgcn_exp2f(sa0[2 * i] - m);
      const float a1 = __builtin_amdgcn_exp2f(sa0[2 * i + 1] - m);
      const float b0 = __builtin_amdgcn_exp2f(sa1[2 * i] - m);
      const float b1 = __builtin_amdgcn_exp2f(sa1[2 * i + 1] - m);
      pk[i] = pack_trunc(a0, a1);
      pk[i + 8] = pack_trunc(b0, b1);
      s16[i] = a0 + a1;
      s16[i + 8] = b0 + b1;
    }
#pragma unroll
    for (int st = 8; st >= 1; st >>= 1)
#pragma unroll
      for (int i = 0; i < st; ++i) s16[i] += s16[i + st];
    lsum += s16[0];
    // ---- P exchange via permlane32_swap (VALU, no DS) + PV ----
#pragma unroll
    for (int f = 0; f < 4; ++f) {
      uint2v s1 = __builtin_amdgcn_permlane32_swap(pk[4 * f + 0], pk[4 * f + 2], false, false);
      uint2v s2 = __builtin_amdgcn_permlane32_swap(pk[4 * f + 1], pk[4 * f + 3], false, false);
      union { int4 i4; short8 s8; } fr;
      fr.i4.x = (int)s1[0];
      fr.i4.y = (int)s2[0];
      fr.i4.z = (int)s1[1];
      fr.i4.w = (int)s2[1];
#pragma unroll
      for (int d = 0; d < 4; ++d) {
        short8 vf = *(const short8*)(vp + vb_[f] + d * 4096);
        oacc[d] = __builtin_amdgcn_mfma_f32_32x32x16_bf16(vf, fr.s8, oacc[d], 0, 0, 0);
      }
    }
  }

  lsum += __shfl_xor(lsum, 32);
  const float inv = 1.f / lsum;
#pragma unroll
  for (int db = 0; db < 4; ++db) {
    __syncthreads();
#pragma unroll
    for (int r = 0; r < 16; r += 2) {
      const float v0 = oacc[db][r] * inv;
      const float v1 = oacc[db][r + 1] * inv;
      const int dloc = (r & 3) + 8 * (r >> 2) + 4 * h;
      *(unsigned*)&ot[w][q5][dloc] = pack_bf16(v0, v1);
    }
    __syncthreads();
    const int qr_ = l >> 1, half = l & 1;
    const short8 ov0 = *(const short8*)&ot[w][qr_][half * 16];
    const short8 ov1 = *(const short8*)&ot[w][qr_][half * 16 + 8];
    const int n2 = qt * 32 + w * 8 + (qr_ >> 2), g2 = qr_ & 3;
    const size_t ob = (size_t)(b * 512 + n2) * 4096 + (hk * 4 + g2) * 128 + db * 32 + half * 16;
    *(short8*)&O[ob] = ov0;
    *(short8*)&O[ob + 8] = ov1;
  }
}

extern "C" void kernel_launch(void* const* d_in, const int* in_sizes, int n_in,
                              void* d_out, int out_size, void* d_ws, size_t ws_size,
                              hipStream_t stream) {
  const float* x = (const float*)d_in[0];
  const float* cosb = (const float*)d_in[1];
  const float* sinb = (const float*)d_in[2];
  const float* lnw = (const float*)d_in[3];
  const float* wq = (const float*)d_in[4];
  const float* wk = (const float*)d_in[5];
  const float* wv = (const float*)d_in[6];
  const float* wo = (const float*)d_in[7];
  const float* kcache = (const float*)d_in[8];
  const float* vcache = (const float*)d_in[9];
  float* out = (float*)d_out;
  char* ws = (char*)d_ws;

  unsigned short* hn    = (unsigned short*)(ws + 0);          // 16.8 MB
  unsigned short* wqkvT = (unsigned short*)(ws + 16777216);   // 50.3 MB
  unsigned short* qkv   = (unsigned short*)(ws + 67108864);   // 25.2 MB
  unsigned short* qrope = (unsigned short*)(ws + 92274688);   // 16.8 MB
  unsigned short* Kall  = (unsigned short*)(ws + 109051904);  // 37.75 MB
  unsigned short* VallT = (unsigned short*)(ws + 146800640);  // 37.75 MB
  unsigned short* attno = hn;     // alias: hn dead after QKV GEMM
  unsigned short* woT   = wqkvT;  // alias: wqkvT dead after QKV GEMM

  rmsnorm_k<<<2048, 256, 0, stream>>>(x, lnw, hn);
  build_wqkvT_k<<<dim3(192, 128), 256, 0, stream>>>(wq, wk, wv, wqkvT);
  gemm2p_k<0><<<768, 256, 0, stream>>>(hn, wqkvT, qkv, nullptr, nullptr, 2048, 6144, 4096, 48);
  rope_k<<<2048, 256, 0, stream>>>(qkv, cosb, sinb, qrope, Kall);
  transpose_u16_k<<<dim3(32, 16, 4), 256, 0, stream>>>(qkv + 5120, 512L * QKV_N, QKV_N,
                                                       VallT + CACHE_C, 4718592L, TOTAL_C);
  cvt_kcache_k<<<16384, 256, 0, stream>>>(kcache, Kall);
  transpose_cvt_k<<<dim3(4, 128, 32), 256, 0, stream>>>(vcache, 4718592L, 128L, 1024,
                                                        VallT, 589824L, TOTAL_C);
  attn3_k<<<512, 256, 0, stream>>>(qrope, Kall, VallT, attno);
  transpose_cvt_k<<<dim3(128, 128, 1), 256, 0, stream>>>(wo, 0L, 0L, 4096, woT, 0L, 4096);
  gemm2p_k<1><<<512, 256, 0, stream>>>(attno, woT, nullptr, out, x, 2048, 4096, 4096, 32);
}